// Round 1
// baseline (961.906 us; speedup 1.0000x reference)
//
#include <hip/hip_runtime.h>

#define NN   50000      // nodes
#define NE   800000     // edges (without self loops)
#define NET  850000     // NE + NN (with self loops)

__device__ __forceinline__ float lrelu(float v) { return v > 0.f ? v : 0.2f * v; }

__device__ __forceinline__ float4 f4zero() { return make_float4(0.f, 0.f, 0.f, 0.f); }

// ---------------------------------------------------------------------------
// GEMM1: h1[N,128] = x[N,128] @ W1[128,128]
// block 256 threads, 64 nodes/block. Per-thread tile: 8 nodes x 4 cols.
// K split in two 64-chunks so LDS = 32KB (W) + 16KB (x) = 48KB <= 64KB.
// ---------------------------------------------------------------------------
__global__ __launch_bounds__(256) void gemm1_kernel(
    const float* __restrict__ x, const float* __restrict__ W, float* __restrict__ h)
{
    __shared__ float Ws[64 * 128];   // [kk][j]
    __shared__ float xs[64 * 64];    // [node][kk]
    const int t  = threadIdx.x;
    const int n0 = blockIdx.x * 64;
    const int jc = t & 31;           // float4 column index: cols 4*jc..4*jc+3
    const int ng = t >> 5;           // node group: nodes ng*8..ng*8+7

    float4 acc[8];
#pragma unroll
    for (int r = 0; r < 8; r++) acc[r] = f4zero();

    float4*       Ws4 = (float4*)Ws;
    float4*       xs4 = (float4*)xs;
    const float4* x4  = (const float4*)x;

    for (int kc = 0; kc < 128; kc += 64) {
        // stage W rows kc..kc+63 (all 128 cols): 2048 float4
        const float4* W4 = (const float4*)(W + kc * 128);
        for (int i = t; i < 64 * 32; i += 256) Ws4[i] = W4[i];
        // stage x[node][kc..kc+63]: 64 nodes x 16 float4
        for (int i = t; i < 64 * 16; i += 256) {
            int node = n0 + (i >> 4);
            xs4[i] = (node < NN) ? x4[node * 32 + (kc >> 2) + (i & 15)] : f4zero();
        }
        __syncthreads();

        for (int kk = 0; kk < 64; kk += 4) {
            float4 w0 = Ws4[(kk + 0) * 32 + jc];
            float4 w1 = Ws4[(kk + 1) * 32 + jc];
            float4 w2 = Ws4[(kk + 2) * 32 + jc];
            float4 w3 = Ws4[(kk + 3) * 32 + jc];
#pragma unroll
            for (int r = 0; r < 8; r++) {
                float4 xv = xs4[((ng * 8 + r) * 64 + kk) >> 2];
                acc[r].x += xv.x * w0.x + xv.y * w1.x + xv.z * w2.x + xv.w * w3.x;
                acc[r].y += xv.x * w0.y + xv.y * w1.y + xv.z * w2.y + xv.w * w3.y;
                acc[r].z += xv.x * w0.z + xv.y * w1.z + xv.z * w2.z + xv.w * w3.z;
                acc[r].w += xv.x * w0.w + xv.y * w1.w + xv.z * w2.w + xv.w * w3.w;
            }
        }
        __syncthreads();
    }

#pragma unroll
    for (int r = 0; r < 8; r++) {
        int node = n0 + ng * 8 + r;
        if (node < NN) ((float4*)h)[node * 32 + jc] = acc[r];
    }
}

// ---------------------------------------------------------------------------
// GEMM2: h2[N,64] = act1[N,128] @ W2[128,64]
// block 256, 64 nodes/block, per-thread tile 4 nodes x 4 cols.
// W2 fully resident (32KB), x staged in two 64-k chunks (16KB). 48KB LDS.
// ---------------------------------------------------------------------------
__global__ __launch_bounds__(256) void gemm2_kernel(
    const float* __restrict__ x, const float* __restrict__ W, float* __restrict__ h)
{
    __shared__ float Ws[128 * 64];   // [k][j]
    __shared__ float xs[64 * 64];
    const int t  = threadIdx.x;
    const int n0 = blockIdx.x * 64;
    const int jc = t & 15;           // cols 4*jc..4*jc+3  (64 cols total)
    const int ng = t >> 4;           // node groups of 4: nodes ng*4..ng*4+3

    float4 acc[4];
#pragma unroll
    for (int r = 0; r < 4; r++) acc[r] = f4zero();

    float4*       Ws4 = (float4*)Ws;
    float4*       xs4 = (float4*)xs;
    const float4* x4  = (const float4*)x;

    // stage full W2: 128*16 float4
    for (int i = t; i < 128 * 16; i += 256) Ws4[i] = ((const float4*)W)[i];

    for (int kc = 0; kc < 128; kc += 64) {
        __syncthreads();   // protects xs reuse (and W before first use)
        for (int i = t; i < 64 * 16; i += 256) {
            int node = n0 + (i >> 4);
            xs4[i] = (node < NN) ? x4[node * 32 + (kc >> 2) + (i & 15)] : f4zero();
        }
        __syncthreads();

        for (int kk = 0; kk < 64; kk += 4) {
            float4 w0 = Ws4[(kc + kk + 0) * 16 + jc];
            float4 w1 = Ws4[(kc + kk + 1) * 16 + jc];
            float4 w2 = Ws4[(kc + kk + 2) * 16 + jc];
            float4 w3 = Ws4[(kc + kk + 3) * 16 + jc];
#pragma unroll
            for (int r = 0; r < 4; r++) {
                float4 xv = xs4[((ng * 4 + r) * 64 + kk) >> 2];
                acc[r].x += xv.x * w0.x + xv.y * w1.x + xv.z * w2.x + xv.w * w3.x;
                acc[r].y += xv.x * w0.y + xv.y * w1.y + xv.z * w2.y + xv.w * w3.y;
                acc[r].z += xv.x * w0.z + xv.y * w1.z + xv.z * w2.z + xv.w * w3.z;
                acc[r].w += xv.x * w0.w + xv.y * w1.w + xv.z * w2.w + xv.w * w3.w;
            }
        }
    }

#pragma unroll
    for (int r = 0; r < 4; r++) {
        int node = n0 + ng * 4 + r;
        if (node < NN) ((float4*)h)[node * 16 + jc] = acc[r];
    }
}

// ---------------------------------------------------------------------------
// alpha1: as1[n,h] = sum_c h1[n,h*32+c]*att_src1[h*32+c]; same for ad1.
// 256 threads = 2 nodes (128 ch each); width-32 shuffle reduce per head.
// ---------------------------------------------------------------------------
__global__ void alpha1_kernel(const float* __restrict__ h,
                              const float* __restrict__ att_s,
                              const float* __restrict__ att_d,
                              float* __restrict__ as, float* __restrict__ ad)
{
    const int t    = threadIdx.x;
    const int node = blockIdx.x * 2 + (t >> 7);
    const int c    = t & 127;
    float v  = h[node * 128 + c];
    float ps = v * att_s[c];
    float pd = v * att_d[c];
#pragma unroll
    for (int off = 16; off > 0; off >>= 1) {
        ps += __shfl_down(ps, off, 32);
        pd += __shfl_down(pd, off, 32);
    }
    if ((c & 31) == 0) {
        as[node * 4 + (c >> 5)] = ps;
        ad[node * 4 + (c >> 5)] = pd;
    }
}

// alpha2: heads=1, 64 channels. 256 threads = 4 nodes; width-64 reduce.
__global__ void alpha2_kernel(const float* __restrict__ h,
                              const float* __restrict__ att_s,
                              const float* __restrict__ att_d,
                              float* __restrict__ as, float* __restrict__ ad)
{
    const int t    = threadIdx.x;
    const int node = blockIdx.x * 4 + (t >> 6);
    const int c    = t & 63;
    float v  = h[node * 64 + c];
    float ps = v * att_s[c];
    float pd = v * att_d[c];
#pragma unroll
    for (int off = 32; off > 0; off >>= 1) {
        ps += __shfl_down(ps, off, 64);
        pd += __shfl_down(pd, off, 64);
    }
    if (c == 0) { as[node] = ps; ad[node] = pd; }
}

// ---------------------------------------------------------------------------
// edge pass 1: ex1[e,h] = exp(leaky(as1[s,h]+ad1[d,h])); denom1[d,h] += ex
// (max-subtraction skipped: |e| small for this data; softmax is invariant)
// ---------------------------------------------------------------------------
__global__ void edge_exp1_kernel(const int* __restrict__ ei,
                                 const float* __restrict__ as,
                                 const float* __restrict__ ad,
                                 float* __restrict__ ex, float* __restrict__ denom)
{
    const int e = blockIdx.x * 256 + threadIdx.x;
    if (e >= NET) return;
    int s, d;
    if (e < NE) { s = ei[e]; d = ei[NE + e]; } else { s = d = e - NE; }
    float4 a = ((const float4*)as)[s];
    float4 b = ((const float4*)ad)[d];
    float4 v;
    v.x = __expf(lrelu(a.x + b.x));
    v.y = __expf(lrelu(a.y + b.y));
    v.z = __expf(lrelu(a.z + b.z));
    v.w = __expf(lrelu(a.w + b.w));
    ((float4*)ex)[e] = v;
    atomicAdd(&denom[d * 4 + 0], v.x);
    atomicAdd(&denom[d * 4 + 1], v.y);
    atomicAdd(&denom[d * 4 + 2], v.z);
    atomicAdd(&denom[d * 4 + 3], v.w);
}

__global__ void edge_exp2_kernel(const int* __restrict__ ei,
                                 const float* __restrict__ as,
                                 const float* __restrict__ ad,
                                 float* __restrict__ ex, float* __restrict__ denom)
{
    const int e = blockIdx.x * 256 + threadIdx.x;
    if (e >= NET) return;
    int s, d;
    if (e < NE) { s = ei[e]; d = ei[NE + e]; } else { s = d = e - NE; }
    float v = __expf(lrelu(as[s] + ad[d]));
    ex[e] = v;
    atomicAdd(&denom[d], v);
}

// ---------------------------------------------------------------------------
// aggregation 1: acc1[d,c] += ex1[e, c/32] * h1[s,c]  (128 ch/edge)
// thread = (edge, channel); 128 consecutive threads share one edge.
// ---------------------------------------------------------------------------
__global__ void agg1_kernel(const int* __restrict__ ei, const float* __restrict__ ex,
                            const float* __restrict__ h, float* __restrict__ acc)
{
    const int idx = blockIdx.x * 256 + threadIdx.x;
    const int e = idx >> 7;
    const int c = idx & 127;
    if (e >= NET) return;
    int s, d;
    if (e < NE) { s = ei[e]; d = ei[NE + e]; } else { s = d = e - NE; }
    float w = ex[e * 4 + (c >> 5)];
    atomicAdd(&acc[d * 128 + c], w * h[s * 128 + c]);
}

// aggregation 2: acc2[d,c] += ex2[e] * h2[s,c]  (64 ch/edge)
__global__ void agg2_kernel(const int* __restrict__ ei, const float* __restrict__ ex,
                            const float* __restrict__ h, float* __restrict__ acc)
{
    const int idx = blockIdx.x * 256 + threadIdx.x;
    const int e = idx >> 6;
    const int c = idx & 63;
    if (e >= NET) return;
    int s, d;
    if (e < NE) { s = ei[e]; d = ei[NE + e]; } else { s = d = e - NE; }
    atomicAdd(&acc[d * 64 + c], ex[e] * h[s * 64 + c]);
}

// finalize 1: act1 = ELU(acc1/(denom1+1e-16) + b1)   (in-place over acc1)
__global__ void finalize1_kernel(const float* __restrict__ acc,
                                 const float* __restrict__ denom,
                                 const float* __restrict__ b1, float* __restrict__ act)
{
    const int idx = blockIdx.x * 256 + threadIdx.x;   // < NN*128 exact
    const int n = idx >> 7, c = idx & 127;
    float v = acc[idx] / (denom[n * 4 + (c >> 5)] + 1e-16f) + b1[c];
    act[idx] = v > 0.f ? v : (__expf(v) - 1.f);
}

// finalize 2: out = acc2/(denom2+1e-16) + b2   (heads=1 -> mean is identity)
__global__ void finalize2_kernel(const float* __restrict__ acc,
                                 const float* __restrict__ denom,
                                 const float* __restrict__ b2, float* __restrict__ out)
{
    const int idx = blockIdx.x * 256 + threadIdx.x;   // < NN*64 exact
    const int n = idx >> 6, c = idx & 63;
    out[idx] = acc[idx] / (denom[n] + 1e-16f) + b2[c];
}

// ---------------------------------------------------------------------------
extern "C" void kernel_launch(void* const* d_in, const int* in_sizes, int n_in,
                              void* d_out, int out_size, void* d_ws, size_t ws_size,
                              hipStream_t stream)
{
    const float* x    = (const float*)d_in[0];
    const int*   ei   = (const int*)  d_in[1];
    const float* W1   = (const float*)d_in[2];
    const float* at_s1= (const float*)d_in[3];
    const float* at_d1= (const float*)d_in[4];
    const float* b1   = (const float*)d_in[5];
    const float* W2   = (const float*)d_in[6];
    const float* at_s2= (const float*)d_in[7];
    const float* at_d2= (const float*)d_in[8];
    const float* b2   = (const float*)d_in[9];
    float*       out  = (float*)d_out;

    // workspace layout (floats)
    float* w      = (float*)d_ws;
    float* acc1   = w;                     // NN*128     (zeroed; becomes act1)
    float* denom1 = acc1   + NN * 128;     // NN*4       (zeroed)
    float* acc2   = denom1 + NN * 4;       // NN*64      (zeroed)
    float* denom2 = acc2   + NN * 64;      // NN         (zeroed)
    float* h1     = denom2 + NN;           // NN*128
    float* as1    = h1     + NN * 128;     // NN*4
    float* ad1    = as1    + NN * 4;       // NN*4
    float* ex1    = ad1    + NN * 4;       // NET*4
    float* h2     = ex1    + NET * 4;      // NN*64
    float* as2    = h2     + NN * 64;      // NN
    float* ad2    = as2    + NN;           // NN
    float* ex2    = ad2    + NN;           // NET

    const size_t zero_bytes = (size_t)(NN * 128 + NN * 4 + NN * 64 + NN) * sizeof(float);
    hipMemsetAsync(d_ws, 0, zero_bytes, stream);

    const int gemm_grid = (NN + 63) / 64;                       // 782
    gemm1_kernel<<<gemm_grid, 256, 0, stream>>>(x, W1, h1);
    alpha1_kernel<<<NN / 2, 256, 0, stream>>>(h1, at_s1, at_d1, as1, ad1);
    edge_exp1_kernel<<<(NET + 255) / 256, 256, 0, stream>>>(ei, as1, ad1, ex1, denom1);
    agg1_kernel<<<(NET * 128) / 256, 256, 0, stream>>>(ei, ex1, h1, acc1);
    finalize1_kernel<<<(NN * 128) / 256, 256, 0, stream>>>(acc1, denom1, b1, acc1);

    gemm2_kernel<<<gemm_grid, 256, 0, stream>>>(acc1, W2, h2);
    alpha2_kernel<<<NN / 4, 256, 0, stream>>>(h2, at_s2, at_d2, as2, ad2);
    edge_exp2_kernel<<<(NET + 255) / 256, 256, 0, stream>>>(ei, as2, ad2, ex2, denom2);
    agg2_kernel<<<(NET * 64) / 256, 256, 0, stream>>>(ei, ex2, h2, acc2);
    finalize2_kernel<<<(NN * 64) / 256, 256, 0, stream>>>(acc2, denom2, b2, out);
}

// Round 2
// 457.697 us; speedup vs baseline: 2.1016x; 2.1016x over previous
//
#include <hip/hip_runtime.h>

#define NN   50000      // nodes
#define NE   800000     // edges (without self loops)
#define NET  850000     // NE + NN (with self loops)
#define NB   ((NN + 255) / 256)   // 196 scan blocks

__device__ __forceinline__ float lrelu(float v) { return v > 0.f ? v : 0.2f * v; }
__device__ __forceinline__ float4 f4zero() { return make_float4(0.f, 0.f, 0.f, 0.f); }

// ---------------------------------------------------------------------------
// GEMM1: h1[N,128] = x[N,128] @ W1[128,128]   (unchanged, verified R1)
// ---------------------------------------------------------------------------
__global__ __launch_bounds__(256) void gemm1_kernel(
    const float* __restrict__ x, const float* __restrict__ W, float* __restrict__ h)
{
    __shared__ float Ws[64 * 128];
    __shared__ float xs[64 * 64];
    const int t  = threadIdx.x;
    const int n0 = blockIdx.x * 64;
    const int jc = t & 31;
    const int ng = t >> 5;

    float4 acc[8];
#pragma unroll
    for (int r = 0; r < 8; r++) acc[r] = f4zero();

    float4*       Ws4 = (float4*)Ws;
    float4*       xs4 = (float4*)xs;
    const float4* x4  = (const float4*)x;

    for (int kc = 0; kc < 128; kc += 64) {
        const float4* W4 = (const float4*)(W + kc * 128);
        for (int i = t; i < 64 * 32; i += 256) Ws4[i] = W4[i];
        for (int i = t; i < 64 * 16; i += 256) {
            int node = n0 + (i >> 4);
            xs4[i] = (node < NN) ? x4[node * 32 + (kc >> 2) + (i & 15)] : f4zero();
        }
        __syncthreads();

        for (int kk = 0; kk < 64; kk += 4) {
            float4 w0 = Ws4[(kk + 0) * 32 + jc];
            float4 w1 = Ws4[(kk + 1) * 32 + jc];
            float4 w2 = Ws4[(kk + 2) * 32 + jc];
            float4 w3 = Ws4[(kk + 3) * 32 + jc];
#pragma unroll
            for (int r = 0; r < 8; r++) {
                float4 xv = xs4[((ng * 8 + r) * 64 + kk) >> 2];
                acc[r].x += xv.x * w0.x + xv.y * w1.x + xv.z * w2.x + xv.w * w3.x;
                acc[r].y += xv.x * w0.y + xv.y * w1.y + xv.z * w2.y + xv.w * w3.y;
                acc[r].z += xv.x * w0.z + xv.y * w1.z + xv.z * w2.z + xv.w * w3.z;
                acc[r].w += xv.x * w0.w + xv.y * w1.w + xv.z * w2.w + xv.w * w3.w;
            }
        }
        __syncthreads();
    }

#pragma unroll
    for (int r = 0; r < 8; r++) {
        int node = n0 + ng * 8 + r;
        if (node < NN) ((float4*)h)[node * 32 + jc] = acc[r];
    }
}

// ---------------------------------------------------------------------------
// GEMM2: h2[N,64] = act1[N,128] @ W2[128,64]   (unchanged, verified R1)
// ---------------------------------------------------------------------------
__global__ __launch_bounds__(256) void gemm2_kernel(
    const float* __restrict__ x, const float* __restrict__ W, float* __restrict__ h)
{
    __shared__ float Ws[128 * 64];
    __shared__ float xs[64 * 64];
    const int t  = threadIdx.x;
    const int n0 = blockIdx.x * 64;
    const int jc = t & 15;
    const int ng = t >> 4;

    float4 acc[4];
#pragma unroll
    for (int r = 0; r < 4; r++) acc[r] = f4zero();

    float4*       Ws4 = (float4*)Ws;
    float4*       xs4 = (float4*)xs;
    const float4* x4  = (const float4*)x;

    for (int i = t; i < 128 * 16; i += 256) Ws4[i] = ((const float4*)W)[i];

    for (int kc = 0; kc < 128; kc += 64) {
        __syncthreads();
        for (int i = t; i < 64 * 16; i += 256) {
            int node = n0 + (i >> 4);
            xs4[i] = (node < NN) ? x4[node * 32 + (kc >> 2) + (i & 15)] : f4zero();
        }
        __syncthreads();

        for (int kk = 0; kk < 64; kk += 4) {
            float4 w0 = Ws4[(kc + kk + 0) * 16 + jc];
            float4 w1 = Ws4[(kc + kk + 1) * 16 + jc];
            float4 w2 = Ws4[(kc + kk + 2) * 16 + jc];
            float4 w3 = Ws4[(kc + kk + 3) * 16 + jc];
#pragma unroll
            for (int r = 0; r < 4; r++) {
                float4 xv = xs4[((ng * 4 + r) * 64 + kk) >> 2];
                acc[r].x += xv.x * w0.x + xv.y * w1.x + xv.z * w2.x + xv.w * w3.x;
                acc[r].y += xv.x * w0.y + xv.y * w1.y + xv.z * w2.y + xv.w * w3.y;
                acc[r].z += xv.x * w0.z + xv.y * w1.z + xv.z * w2.z + xv.w * w3.z;
                acc[r].w += xv.x * w0.w + xv.y * w1.w + xv.z * w2.w + xv.w * w3.w;
            }
        }
    }

#pragma unroll
    for (int r = 0; r < 4; r++) {
        int node = n0 + ng * 4 + r;
        if (node < NN) ((float4*)h)[node * 16 + jc] = acc[r];
    }
}

// ---------------------------------------------------------------------------
// alpha kernels (unchanged)
// ---------------------------------------------------------------------------
__global__ void alpha1_kernel(const float* __restrict__ h,
                              const float* __restrict__ att_s,
                              const float* __restrict__ att_d,
                              float* __restrict__ as, float* __restrict__ ad)
{
    const int t    = threadIdx.x;
    const int node = blockIdx.x * 2 + (t >> 7);
    const int c    = t & 127;
    float v  = h[node * 128 + c];
    float ps = v * att_s[c];
    float pd = v * att_d[c];
#pragma unroll
    for (int off = 16; off > 0; off >>= 1) {
        ps += __shfl_down(ps, off, 32);
        pd += __shfl_down(pd, off, 32);
    }
    if ((c & 31) == 0) {
        as[node * 4 + (c >> 5)] = ps;
        ad[node * 4 + (c >> 5)] = pd;
    }
}

__global__ void alpha2_kernel(const float* __restrict__ h,
                              const float* __restrict__ att_s,
                              const float* __restrict__ att_d,
                              float* __restrict__ as, float* __restrict__ ad)
{
    const int t    = threadIdx.x;
    const int node = blockIdx.x * 4 + (t >> 6);
    const int c    = t & 63;
    float v  = h[node * 64 + c];
    float ps = v * att_s[c];
    float pd = v * att_d[c];
#pragma unroll
    for (int off = 32; off > 0; off >>= 1) {
        ps += __shfl_down(ps, off, 64);
        pd += __shfl_down(pd, off, 64);
    }
    if (c == 0) { as[node] = ps; ad[node] = pd; }
}

// ---------------------------------------------------------------------------
// CSR build: count -> scan (3 kernels) -> scatter. Reused by both layers.
// ---------------------------------------------------------------------------
__global__ void count_kernel(const int* __restrict__ ei, int* __restrict__ cnt)
{
    const int e = blockIdx.x * 256 + threadIdx.x;
    if (e >= NET) return;
    const int d = (e < NE) ? ei[NE + e] : e - NE;
    atomicAdd(&cnt[d], 1);
}

// inclusive block scan (Hillis-Steele) -> exclusive-within-block + block sums
__global__ __launch_bounds__(256) void scanA_kernel(const int* __restrict__ cnt,
                                                    int* __restrict__ excl,
                                                    int* __restrict__ bsum)
{
    __shared__ int sh[256];
    const int tid = threadIdx.x;
    const int i   = blockIdx.x * 256 + tid;
    const int v   = (i < NN) ? cnt[i] : 0;
    sh[tid] = v;
    __syncthreads();
#pragma unroll
    for (int off = 1; off < 256; off <<= 1) {
        int t = (tid >= off) ? sh[tid - off] : 0;
        __syncthreads();
        sh[tid] += t;
        __syncthreads();
    }
    if (i < NN) excl[i] = sh[tid] - v;
    if (tid == 255) bsum[blockIdx.x] = sh[255];
}

__global__ __launch_bounds__(256) void scanB_kernel(int* __restrict__ bsum,
                                                    int* __restrict__ boff)
{
    __shared__ int sh[256];
    const int tid = threadIdx.x;
    const int v   = (tid < NB) ? bsum[tid] : 0;
    sh[tid] = v;
    __syncthreads();
#pragma unroll
    for (int off = 1; off < 256; off <<= 1) {
        int t = (tid >= off) ? sh[tid - off] : 0;
        __syncthreads();
        sh[tid] += t;
        __syncthreads();
    }
    if (tid < NB) boff[tid] = sh[tid] - v;   // exclusive
}

__global__ void scanC_kernel(const int* __restrict__ excl, const int* __restrict__ boff,
                             int* __restrict__ row_ptr, int* __restrict__ cursor)
{
    const int i = blockIdx.x * 256 + threadIdx.x;
    if (i < NN) {
        int r = excl[i] + boff[i >> 8];
        row_ptr[i] = r;
        cursor[i]  = r;
    } else if (i == NN) {
        row_ptr[NN] = NET;
    }
}

__global__ void scatter_kernel(const int* __restrict__ ei, int* __restrict__ cursor,
                               int* __restrict__ col)
{
    const int e = blockIdx.x * 256 + threadIdx.x;
    if (e >= NET) return;
    int s, d;
    if (e < NE) { s = ei[e]; d = ei[NE + e]; } else { s = d = e - NE; }
    const int slot = atomicAdd(&cursor[d], 1);
    col[slot] = s;
}

// ---------------------------------------------------------------------------
// Fused layer-1 tail: per-node softmax + aggregate + normalize + bias + ELU.
// One 64-lane wave per dst node; lane owns channels {lane, lane+64}.
// head(c) = c>>5: lane's heads are (lane>>5) and (lane>>5)+2.
// ---------------------------------------------------------------------------
__global__ __launch_bounds__(256) void agg1_fused_kernel(
    const int* __restrict__ row_ptr, const int* __restrict__ col,
    const float* __restrict__ h, const float* __restrict__ as,
    const float* __restrict__ ad, const float* __restrict__ b1,
    float* __restrict__ act)
{
    const int d    = (blockIdx.x * 256 + threadIdx.x) >> 6;
    const int lane = threadIdx.x & 63;
    if (d >= NN) return;
    const int h0 = lane >> 5, h1i = h0 + 2;
    const float ad0 = ad[d * 4 + h0];
    const float ad1 = ad[d * 4 + h1i];
    const int beg = row_ptr[d], end = row_ptr[d + 1];

    float acc0 = 0.f, acc1 = 0.f, den0 = 0.f, den1 = 0.f;
    for (int j = beg; j < end; j++) {
        const int s = col[j];
        const float w0 = __expf(lrelu(as[s * 4 + h0] + ad0));
        const float w1 = __expf(lrelu(as[s * 4 + h1i] + ad1));
        den0 += w0;
        den1 += w1;
        acc0 += w0 * h[s * 128 + lane];
        acc1 += w1 * h[s * 128 + 64 + lane];
    }
    float v0 = acc0 / (den0 + 1e-16f) + b1[lane];
    float v1 = acc1 / (den1 + 1e-16f) + b1[64 + lane];
    act[d * 128 + lane]      = v0 > 0.f ? v0 : (__expf(v0) - 1.f);
    act[d * 128 + 64 + lane] = v1 > 0.f ? v1 : (__expf(v1) - 1.f);
}

// Fused layer-2 tail: heads=1, 64 ch. One wave per node, lane = channel.
__global__ __launch_bounds__(256) void agg2_fused_kernel(
    const int* __restrict__ row_ptr, const int* __restrict__ col,
    const float* __restrict__ h, const float* __restrict__ as,
    const float* __restrict__ ad, const float* __restrict__ b2,
    float* __restrict__ out)
{
    const int d    = (blockIdx.x * 256 + threadIdx.x) >> 6;
    const int lane = threadIdx.x & 63;
    if (d >= NN) return;
    const float adv = ad[d];
    const int beg = row_ptr[d], end = row_ptr[d + 1];

    float acc = 0.f, den = 0.f;
    for (int j = beg; j < end; j++) {
        const int s = col[j];
        const float w = __expf(lrelu(as[s] + adv));
        den += w;
        acc += w * h[s * 64 + lane];
    }
    out[d * 64 + lane] = acc / (den + 1e-16f) + b2[lane];
}

// ---------------------------------------------------------------------------
extern "C" void kernel_launch(void* const* d_in, const int* in_sizes, int n_in,
                              void* d_out, int out_size, void* d_ws, size_t ws_size,
                              hipStream_t stream)
{
    const float* x    = (const float*)d_in[0];
    const int*   ei   = (const int*)  d_in[1];
    const float* W1   = (const float*)d_in[2];
    const float* at_s1= (const float*)d_in[3];
    const float* at_d1= (const float*)d_in[4];
    const float* b1   = (const float*)d_in[5];
    const float* W2   = (const float*)d_in[6];
    const float* at_s2= (const float*)d_in[7];
    const float* at_d2= (const float*)d_in[8];
    const float* b2   = (const float*)d_in[9];
    float*       out  = (float*)d_out;

    // workspace layout
    float* fw   = (float*)d_ws;
    float* h1   = fw;                  // NN*128
    float* act1 = h1   + NN * 128;     // NN*128
    float* h2   = act1 + NN * 128;     // NN*64
    float* as1  = h2   + NN * 64;      // NN*4
    float* ad1  = as1  + NN * 4;       // NN*4
    float* as2  = ad1  + NN * 4;       // NN
    float* ad2  = as2  + NN;           // NN
    int*   iw      = (int*)(ad2 + NN);
    int*   cnt     = iw;               // NN   (zeroed)
    int*   excl    = cnt     + NN;     // NN
    int*   row_ptr = excl    + NN;     // NN+1
    int*   cursor  = row_ptr + NN + 1; // NN
    int*   bsum    = cursor  + NN;     // 256
    int*   boff    = bsum    + 256;    // 256
    int*   col     = boff    + 256;    // NET

    hipMemsetAsync(cnt, 0, NN * sizeof(int), stream);

    const int eg = (NET + 255) / 256;
    // CSR build (reused by both layers)
    count_kernel  <<<eg, 256, 0, stream>>>(ei, cnt);
    scanA_kernel  <<<NB, 256, 0, stream>>>(cnt, excl, bsum);
    scanB_kernel  <<<1,  256, 0, stream>>>(bsum, boff);
    scanC_kernel  <<<(NN + 256) / 256 + 1, 256, 0, stream>>>(excl, boff, row_ptr, cursor);
    scatter_kernel<<<eg, 256, 0, stream>>>(ei, cursor, col);

    const int gemm_grid = (NN + 63) / 64;
    const int node_wave_grid = (NN + 3) / 4;   // 4 waves (nodes) per 256-thr block

    // layer 1
    gemm1_kernel     <<<gemm_grid, 256, 0, stream>>>(x, W1, h1);
    alpha1_kernel    <<<NN / 2, 256, 0, stream>>>(h1, at_s1, at_d1, as1, ad1);
    agg1_fused_kernel<<<node_wave_grid, 256, 0, stream>>>(row_ptr, col, h1, as1, ad1, b1, act1);

    // layer 2
    gemm2_kernel     <<<gemm_grid, 256, 0, stream>>>(act1, W2, h2);
    alpha2_kernel    <<<NN / 4, 256, 0, stream>>>(h2, at_s2, at_d2, as2, ad2);
    agg2_fused_kernel<<<node_wave_grid, 256, 0, stream>>>(row_ptr, col, h2, as2, ad2, b2, out);
}

// Round 3
// 372.519 us; speedup vs baseline: 2.5822x; 1.2287x over previous
//
#include <hip/hip_runtime.h>

#define NN   50000      // nodes
#define NE   800000     // edges (without self loops)
#define NET  850000     // NE + NN (with self loops)
#define NB   ((NN + 255) / 256)   // 196 scan blocks

__device__ __forceinline__ float lrelu(float v) { return fmaxf(v, 0.2f * v); }
__device__ __forceinline__ float4 f4zero() { return make_float4(0.f, 0.f, 0.f, 0.f); }

// ---------------------------------------------------------------------------
// GEMM1: h1[N,128] = x[N,128] @ W1[128,128]   (unchanged, verified R1)
// ---------------------------------------------------------------------------
__global__ __launch_bounds__(256) void gemm1_kernel(
    const float* __restrict__ x, const float* __restrict__ W, float* __restrict__ h)
{
    __shared__ float Ws[64 * 128];
    __shared__ float xs[64 * 64];
    const int t  = threadIdx.x;
    const int n0 = blockIdx.x * 64;
    const int jc = t & 31;
    const int ng = t >> 5;

    float4 acc[8];
#pragma unroll
    for (int r = 0; r < 8; r++) acc[r] = f4zero();

    float4*       Ws4 = (float4*)Ws;
    float4*       xs4 = (float4*)xs;
    const float4* x4  = (const float4*)x;

    for (int kc = 0; kc < 128; kc += 64) {
        const float4* W4 = (const float4*)(W + kc * 128);
        for (int i = t; i < 64 * 32; i += 256) Ws4[i] = W4[i];
        for (int i = t; i < 64 * 16; i += 256) {
            int node = n0 + (i >> 4);
            xs4[i] = (node < NN) ? x4[node * 32 + (kc >> 2) + (i & 15)] : f4zero();
        }
        __syncthreads();

        for (int kk = 0; kk < 64; kk += 4) {
            float4 w0 = Ws4[(kk + 0) * 32 + jc];
            float4 w1 = Ws4[(kk + 1) * 32 + jc];
            float4 w2 = Ws4[(kk + 2) * 32 + jc];
            float4 w3 = Ws4[(kk + 3) * 32 + jc];
#pragma unroll
            for (int r = 0; r < 8; r++) {
                float4 xv = xs4[((ng * 8 + r) * 64 + kk) >> 2];
                acc[r].x += xv.x * w0.x + xv.y * w1.x + xv.z * w2.x + xv.w * w3.x;
                acc[r].y += xv.x * w0.y + xv.y * w1.y + xv.z * w2.y + xv.w * w3.y;
                acc[r].z += xv.x * w0.z + xv.y * w1.z + xv.z * w2.z + xv.w * w3.z;
                acc[r].w += xv.x * w0.w + xv.y * w1.w + xv.z * w2.w + xv.w * w3.w;
            }
        }
        __syncthreads();
    }

#pragma unroll
    for (int r = 0; r < 8; r++) {
        int node = n0 + ng * 8 + r;
        if (node < NN) ((float4*)h)[node * 32 + jc] = acc[r];
    }
}

// ---------------------------------------------------------------------------
// GEMM2: h2[N,64] = act1[N,128] @ W2[128,64]   (unchanged, verified R1)
// ---------------------------------------------------------------------------
__global__ __launch_bounds__(256) void gemm2_kernel(
    const float* __restrict__ x, const float* __restrict__ W, float* __restrict__ h)
{
    __shared__ float Ws[128 * 64];
    __shared__ float xs[64 * 64];
    const int t  = threadIdx.x;
    const int n0 = blockIdx.x * 64;
    const int jc = t & 15;
    const int ng = t >> 4;

    float4 acc[4];
#pragma unroll
    for (int r = 0; r < 4; r++) acc[r] = f4zero();

    float4*       Ws4 = (float4*)Ws;
    float4*       xs4 = (float4*)xs;
    const float4* x4  = (const float4*)x;

    for (int i = t; i < 128 * 16; i += 256) Ws4[i] = ((const float4*)W)[i];

    for (int kc = 0; kc < 128; kc += 64) {
        __syncthreads();
        for (int i = t; i < 64 * 16; i += 256) {
            int node = n0 + (i >> 4);
            xs4[i] = (node < NN) ? x4[node * 32 + (kc >> 2) + (i & 15)] : f4zero();
        }
        __syncthreads();

        for (int kk = 0; kk < 64; kk += 4) {
            float4 w0 = Ws4[(kc + kk + 0) * 16 + jc];
            float4 w1 = Ws4[(kc + kk + 1) * 16 + jc];
            float4 w2 = Ws4[(kc + kk + 2) * 16 + jc];
            float4 w3 = Ws4[(kc + kk + 3) * 16 + jc];
#pragma unroll
            for (int r = 0; r < 4; r++) {
                float4 xv = xs4[((ng * 4 + r) * 64 + kk) >> 2];
                acc[r].x += xv.x * w0.x + xv.y * w1.x + xv.z * w2.x + xv.w * w3.x;
                acc[r].y += xv.x * w0.y + xv.y * w1.y + xv.z * w2.y + xv.w * w3.y;
                acc[r].z += xv.x * w0.z + xv.y * w1.z + xv.z * w2.z + xv.w * w3.z;
                acc[r].w += xv.x * w0.w + xv.y * w1.w + xv.z * w2.w + xv.w * w3.w;
            }
        }
    }

#pragma unroll
    for (int r = 0; r < 4; r++) {
        int node = n0 + ng * 4 + r;
        if (node < NN) ((float4*)h)[node * 16 + jc] = acc[r];
    }
}

// ---------------------------------------------------------------------------
// alpha kernels (unchanged)
// ---------------------------------------------------------------------------
__global__ void alpha1_kernel(const float* __restrict__ h,
                              const float* __restrict__ att_s,
                              const float* __restrict__ att_d,
                              float* __restrict__ as, float* __restrict__ ad)
{
    const int t    = threadIdx.x;
    const int node = blockIdx.x * 2 + (t >> 7);
    const int c    = t & 127;
    float v  = h[node * 128 + c];
    float ps = v * att_s[c];
    float pd = v * att_d[c];
#pragma unroll
    for (int off = 16; off > 0; off >>= 1) {
        ps += __shfl_down(ps, off, 32);
        pd += __shfl_down(pd, off, 32);
    }
    if ((c & 31) == 0) {
        as[node * 4 + (c >> 5)] = ps;
        ad[node * 4 + (c >> 5)] = pd;
    }
}

__global__ void alpha2_kernel(const float* __restrict__ h,
                              const float* __restrict__ att_s,
                              const float* __restrict__ att_d,
                              float* __restrict__ as, float* __restrict__ ad)
{
    const int t    = threadIdx.x;
    const int node = blockIdx.x * 4 + (t >> 6);
    const int c    = t & 63;
    float v  = h[node * 64 + c];
    float ps = v * att_s[c];
    float pd = v * att_d[c];
#pragma unroll
    for (int off = 32; off > 0; off >>= 1) {
        ps += __shfl_down(ps, off, 64);
        pd += __shfl_down(pd, off, 64);
    }
    if (c == 0) { as[node] = ps; ad[node] = pd; }
}

// ---------------------------------------------------------------------------
// CSR build: count -> scan (3 kernels) -> scatter. Reused by both layers.
// ---------------------------------------------------------------------------
__global__ void count_kernel(const int* __restrict__ ei, int* __restrict__ cnt)
{
    const int e = blockIdx.x * 256 + threadIdx.x;
    if (e >= NET) return;
    const int d = (e < NE) ? ei[NE + e] : e - NE;
    atomicAdd(&cnt[d], 1);
}

__global__ __launch_bounds__(256) void scanA_kernel(const int* __restrict__ cnt,
                                                    int* __restrict__ excl,
                                                    int* __restrict__ bsum)
{
    __shared__ int sh[256];
    const int tid = threadIdx.x;
    const int i   = blockIdx.x * 256 + tid;
    const int v   = (i < NN) ? cnt[i] : 0;
    sh[tid] = v;
    __syncthreads();
#pragma unroll
    for (int off = 1; off < 256; off <<= 1) {
        int t = (tid >= off) ? sh[tid - off] : 0;
        __syncthreads();
        sh[tid] += t;
        __syncthreads();
    }
    if (i < NN) excl[i] = sh[tid] - v;
    if (tid == 255) bsum[blockIdx.x] = sh[255];
}

__global__ __launch_bounds__(256) void scanB_kernel(int* __restrict__ bsum,
                                                    int* __restrict__ boff)
{
    __shared__ int sh[256];
    const int tid = threadIdx.x;
    const int v   = (tid < NB) ? bsum[tid] : 0;
    sh[tid] = v;
    __syncthreads();
#pragma unroll
    for (int off = 1; off < 256; off <<= 1) {
        int t = (tid >= off) ? sh[tid - off] : 0;
        __syncthreads();
        sh[tid] += t;
        __syncthreads();
    }
    if (tid < NB) boff[tid] = sh[tid] - v;
}

__global__ void scanC_kernel(const int* __restrict__ excl, const int* __restrict__ boff,
                             int* __restrict__ row_ptr, int* __restrict__ cursor)
{
    const int i = blockIdx.x * 256 + threadIdx.x;
    if (i < NN) {
        int r = excl[i] + boff[i >> 8];
        row_ptr[i] = r;
        cursor[i]  = r;
    } else if (i == NN) {
        row_ptr[NN] = NET;
    }
}

__global__ void scatter_kernel(const int* __restrict__ ei, int* __restrict__ cursor,
                               int* __restrict__ col)
{
    const int e = blockIdx.x * 256 + threadIdx.x;
    if (e >= NET) return;
    int s, d;
    if (e < NE) { s = ei[e]; d = ei[NE + e]; } else { s = d = e - NE; }
    const int slot = atomicAdd(&cursor[d], 1);
    col[slot] = s;
}

// ---------------------------------------------------------------------------
// Fused layer-1 tail, latency-batched:
// one wave per dst; one vector load grabs <=64 col entries; src indices
// broadcast via readlane (SGPR); 8 edges' gathers issued back-to-back.
// Tail edges clamp to a valid src, weight masked to 0 (branchless).
// ---------------------------------------------------------------------------
__global__ __launch_bounds__(256) void agg1_fused_kernel(
    const int* __restrict__ row_ptr, const int* __restrict__ col,
    const float* __restrict__ h, const float* __restrict__ as,
    const float* __restrict__ ad, const float* __restrict__ b1,
    float* __restrict__ act)
{
    const int d    = (blockIdx.x * 256 + threadIdx.x) >> 6;
    const int lane = threadIdx.x & 63;
    if (d >= NN) return;
    const int hsel = lane >> 5;                 // head pair select: {0,2} or {1,3}
    const float4 adv = ((const float4*)ad)[d];
    const float ad0 = hsel ? adv.y : adv.x;
    const float ad1 = hsel ? adv.w : adv.z;
    const int beg = row_ptr[d], end = row_ptr[d + 1];   // deg >= 1 (self loop)

    float acc0 = 0.f, acc1 = 0.f, den0 = 0.f, den1 = 0.f;

    for (int jb = beg; jb < end; jb += 64) {
        const int cnt = min(64, end - jb);
        const int sv  = col[jb + min(lane, cnt - 1)];   // one load / 64 edges
        for (int u = 0; u < cnt; u += 8) {
            int s[8];
#pragma unroll
            for (int k = 0; k < 8; k++)
                s[k] = __builtin_amdgcn_readlane(sv, min(u + k, cnt - 1));
            float4 av[8];
            float  g0[8], g1[8];
#pragma unroll
            for (int k = 0; k < 8; k++) {
                av[k] = ((const float4*)as)[s[k]];
                g0[k] = h[s[k] * 128 + lane];
                g1[k] = h[s[k] * 128 + 64 + lane];
            }
#pragma unroll
            for (int k = 0; k < 8; k++) {
                const float m  = (u + k < cnt) ? 1.f : 0.f;
                const float a0 = hsel ? av[k].y : av[k].x;
                const float a1 = hsel ? av[k].w : av[k].z;
                const float w0 = __expf(lrelu(a0 + ad0)) * m;
                const float w1 = __expf(lrelu(a1 + ad1)) * m;
                den0 += w0;  den1 += w1;
                acc0 += w0 * g0[k];
                acc1 += w1 * g1[k];
            }
        }
    }
    float v0 = acc0 / (den0 + 1e-16f) + b1[lane];
    float v1 = acc1 / (den1 + 1e-16f) + b1[64 + lane];
    act[d * 128 + lane]      = v0 > 0.f ? v0 : (__expf(v0) - 1.f);
    act[d * 128 + 64 + lane] = v1 > 0.f ? v1 : (__expf(v1) - 1.f);
}

// Fused layer-2 tail, same batching. heads=1, 64 ch, lane = channel.
__global__ __launch_bounds__(256) void agg2_fused_kernel(
    const int* __restrict__ row_ptr, const int* __restrict__ col,
    const float* __restrict__ h, const float* __restrict__ as,
    const float* __restrict__ ad, const float* __restrict__ b2,
    float* __restrict__ out)
{
    const int d    = (blockIdx.x * 256 + threadIdx.x) >> 6;
    const int lane = threadIdx.x & 63;
    if (d >= NN) return;
    const float adv = ad[d];
    const int beg = row_ptr[d], end = row_ptr[d + 1];

    float acc = 0.f, den = 0.f;
    for (int jb = beg; jb < end; jb += 64) {
        const int cnt = min(64, end - jb);
        const int sv  = col[jb + min(lane, cnt - 1)];
        for (int u = 0; u < cnt; u += 8) {
            int s[8];
#pragma unroll
            for (int k = 0; k < 8; k++)
                s[k] = __builtin_amdgcn_readlane(sv, min(u + k, cnt - 1));
            float a[8], g[8];
#pragma unroll
            for (int k = 0; k < 8; k++) {
                a[k] = as[s[k]];
                g[k] = h[s[k] * 64 + lane];
            }
#pragma unroll
            for (int k = 0; k < 8; k++) {
                const float m = (u + k < cnt) ? 1.f : 0.f;
                const float w = __expf(lrelu(a[k] + adv)) * m;
                den += w;
                acc += w * g[k];
            }
        }
    }
    out[d * 64 + lane] = acc / (den + 1e-16f) + b2[lane];
}

// ---------------------------------------------------------------------------
extern "C" void kernel_launch(void* const* d_in, const int* in_sizes, int n_in,
                              void* d_out, int out_size, void* d_ws, size_t ws_size,
                              hipStream_t stream)
{
    const float* x    = (const float*)d_in[0];
    const int*   ei   = (const int*)  d_in[1];
    const float* W1   = (const float*)d_in[2];
    const float* at_s1= (const float*)d_in[3];
    const float* at_d1= (const float*)d_in[4];
    const float* b1   = (const float*)d_in[5];
    const float* W2   = (const float*)d_in[6];
    const float* at_s2= (const float*)d_in[7];
    const float* at_d2= (const float*)d_in[8];
    const float* b2   = (const float*)d_in[9];
    float*       out  = (float*)d_out;

    // workspace layout
    float* fw   = (float*)d_ws;
    float* h1   = fw;                  // NN*128
    float* act1 = h1   + NN * 128;     // NN*128
    float* h2   = act1 + NN * 128;     // NN*64
    float* as1  = h2   + NN * 64;      // NN*4
    float* ad1  = as1  + NN * 4;       // NN*4
    float* as2  = ad1  + NN * 4;       // NN
    float* ad2  = as2  + NN;           // NN
    int*   iw      = (int*)(ad2 + NN);
    int*   cnt     = iw;               // NN   (zeroed)
    int*   excl    = cnt     + NN;     // NN
    int*   row_ptr = excl    + NN;     // NN+1
    int*   cursor  = row_ptr + NN + 1; // NN
    int*   bsum    = cursor  + NN;     // 256
    int*   boff    = bsum    + 256;    // 256
    int*   col     = boff    + 256;    // NET

    hipMemsetAsync(cnt, 0, NN * sizeof(int), stream);

    const int eg = (NET + 255) / 256;
    count_kernel  <<<eg, 256, 0, stream>>>(ei, cnt);
    scanA_kernel  <<<NB, 256, 0, stream>>>(cnt, excl, bsum);
    scanB_kernel  <<<1,  256, 0, stream>>>(bsum, boff);
    scanC_kernel  <<<(NN + 256) / 256 + 1, 256, 0, stream>>>(excl, boff, row_ptr, cursor);
    scatter_kernel<<<eg, 256, 0, stream>>>(ei, cursor, col);

    const int gemm_grid = (NN + 63) / 64;
    const int node_wave_grid = (NN + 3) / 4;

    // layer 1
    gemm1_kernel     <<<gemm_grid, 256, 0, stream>>>(x, W1, h1);
    alpha1_kernel    <<<NN / 2, 256, 0, stream>>>(h1, at_s1, at_d1, as1, ad1);
    agg1_fused_kernel<<<node_wave_grid, 256, 0, stream>>>(row_ptr, col, h1, as1, ad1, b1, act1);

    // layer 2
    gemm2_kernel     <<<gemm_grid, 256, 0, stream>>>(act1, W2, h2);
    alpha2_kernel    <<<NN / 4, 256, 0, stream>>>(h2, at_s2, at_d2, as2, ad2);
    agg2_fused_kernel<<<node_wave_grid, 256, 0, stream>>>(row_ptr, col, h2, as2, ad2, b2, out);
}

// Round 4
// 340.885 us; speedup vs baseline: 2.8218x; 1.0928x over previous
//
#include <hip/hip_runtime.h>

#define NN   50000      // nodes
#define NE   800000     // edges (without self loops)
#define NET  850000     // NE + NN (with self loops)
#define NB   ((NN + 255) / 256)   // 196 scan blocks

typedef __fp16 half2_t __attribute__((ext_vector_type(2)));

__device__ __forceinline__ float lrelu(float v) { return fmaxf(v, 0.2f * v); }
__device__ __forceinline__ float4 f4zero() { return make_float4(0.f, 0.f, 0.f, 0.f); }
__device__ __forceinline__ unsigned pk16(float a, float b) {
    half2_t h = __builtin_amdgcn_cvt_pkrtz(a, b);
    return __builtin_bit_cast(unsigned, h);
}
__device__ __forceinline__ float2 unpk16(unsigned u) {
    half2_t h = __builtin_bit_cast(half2_t, u);
    return make_float2((float)h.x, (float)h.y);
}

// ---------------------------------------------------------------------------
// GEMM1 + alpha1 fused: hh[N,128 fp16] = x @ W1; as1/ad1 = h . att_{s,d}
// block 256, 64 nodes/block, per-thread tile 8 nodes x 4 cols.
// Epilogue: per-head dot via 8-lane shuffle reduce; h written fp16-packed ONLY.
// ---------------------------------------------------------------------------
__global__ __launch_bounds__(256) void gemm1_alpha_kernel(
    const float* __restrict__ x, const float* __restrict__ W,
    const float* __restrict__ att_s, const float* __restrict__ att_d,
    unsigned* __restrict__ hh, float* __restrict__ as, float* __restrict__ ad)
{
    __shared__ float Ws[64 * 128];
    __shared__ float xs[64 * 64];
    const int t  = threadIdx.x;
    const int n0 = blockIdx.x * 64;
    const int jc = t & 31;
    const int ng = t >> 5;

    float4 acc[8];
#pragma unroll
    for (int r = 0; r < 8; r++) acc[r] = f4zero();

    float4*       Ws4 = (float4*)Ws;
    float4*       xs4 = (float4*)xs;
    const float4* x4  = (const float4*)x;

    for (int kc = 0; kc < 128; kc += 64) {
        const float4* W4 = (const float4*)(W + kc * 128);
        for (int i = t; i < 64 * 32; i += 256) Ws4[i] = W4[i];
        for (int i = t; i < 64 * 16; i += 256) {
            int node = n0 + (i >> 4);
            xs4[i] = (node < NN) ? x4[node * 32 + (kc >> 2) + (i & 15)] : f4zero();
        }
        __syncthreads();

        for (int kk = 0; kk < 64; kk += 4) {
            float4 w0 = Ws4[(kk + 0) * 32 + jc];
            float4 w1 = Ws4[(kk + 1) * 32 + jc];
            float4 w2 = Ws4[(kk + 2) * 32 + jc];
            float4 w3 = Ws4[(kk + 3) * 32 + jc];
#pragma unroll
            for (int r = 0; r < 8; r++) {
                float4 xv = xs4[((ng * 8 + r) * 64 + kk) >> 2];
                acc[r].x += xv.x * w0.x + xv.y * w1.x + xv.z * w2.x + xv.w * w3.x;
                acc[r].y += xv.x * w0.y + xv.y * w1.y + xv.z * w2.y + xv.w * w3.y;
                acc[r].z += xv.x * w0.z + xv.y * w1.z + xv.z * w2.z + xv.w * w3.z;
                acc[r].w += xv.x * w0.w + xv.y * w1.w + xv.z * w2.w + xv.w * w3.w;
            }
        }
        __syncthreads();
    }

    const float4 sa4 = ((const float4*)att_s)[jc];
    const float4 da4 = ((const float4*)att_d)[jc];
#pragma unroll
    for (int r = 0; r < 8; r++) {
        const int node = n0 + ng * 8 + r;
        const bool ok  = node < NN;
        if (ok) {
            uint2 hp;
            hp.x = pk16(acc[r].x, acc[r].y);
            hp.y = pk16(acc[r].z, acc[r].w);
            ((uint2*)hh)[node * 32 + jc] = hp;
        }
        float ps = acc[r].x * sa4.x + acc[r].y * sa4.y + acc[r].z * sa4.z + acc[r].w * sa4.w;
        float pd = acc[r].x * da4.x + acc[r].y * da4.y + acc[r].z * da4.z + acc[r].w * da4.w;
        ps += __shfl_down(ps, 4);  pd += __shfl_down(pd, 4);
        ps += __shfl_down(ps, 2);  pd += __shfl_down(pd, 2);
        ps += __shfl_down(ps, 1);  pd += __shfl_down(pd, 1);
        if (ok && (jc & 7) == 0) {
            as[node * 4 + (jc >> 3)] = ps;
            ad[node * 4 + (jc >> 3)] = pd;
        }
    }
}

// ---------------------------------------------------------------------------
// GEMM2 + alpha2 fused: h2[N,64 fp32] = act1 @ W2; as2/ad2 scalars per node.
// ---------------------------------------------------------------------------
__global__ __launch_bounds__(256) void gemm2_alpha_kernel(
    const float* __restrict__ x, const float* __restrict__ W,
    const float* __restrict__ att_s, const float* __restrict__ att_d,
    float* __restrict__ h, float* __restrict__ as, float* __restrict__ ad)
{
    __shared__ float Ws[128 * 64];
    __shared__ float xs[64 * 64];
    const int t  = threadIdx.x;
    const int n0 = blockIdx.x * 64;
    const int jc = t & 15;
    const int ng = t >> 4;

    float4 acc[4];
#pragma unroll
    for (int r = 0; r < 4; r++) acc[r] = f4zero();

    float4*       Ws4 = (float4*)Ws;
    float4*       xs4 = (float4*)xs;
    const float4* x4  = (const float4*)x;

    for (int i = t; i < 128 * 16; i += 256) Ws4[i] = ((const float4*)W)[i];

    for (int kc = 0; kc < 128; kc += 64) {
        __syncthreads();
        for (int i = t; i < 64 * 16; i += 256) {
            int node = n0 + (i >> 4);
            xs4[i] = (node < NN) ? x4[node * 32 + (kc >> 2) + (i & 15)] : f4zero();
        }
        __syncthreads();

        for (int kk = 0; kk < 64; kk += 4) {
            float4 w0 = Ws4[(kc + kk + 0) * 16 + jc];
            float4 w1 = Ws4[(kc + kk + 1) * 16 + jc];
            float4 w2 = Ws4[(kc + kk + 2) * 16 + jc];
            float4 w3 = Ws4[(kc + kk + 3) * 16 + jc];
#pragma unroll
            for (int r = 0; r < 4; r++) {
                float4 xv = xs4[((ng * 4 + r) * 64 + kk) >> 2];
                acc[r].x += xv.x * w0.x + xv.y * w1.x + xv.z * w2.x + xv.w * w3.x;
                acc[r].y += xv.x * w0.y + xv.y * w1.y + xv.z * w2.y + xv.w * w3.y;
                acc[r].z += xv.x * w0.z + xv.y * w1.z + xv.z * w2.z + xv.w * w3.z;
                acc[r].w += xv.x * w0.w + xv.y * w1.w + xv.z * w2.w + xv.w * w3.w;
            }
        }
    }

    const float4 sa4 = ((const float4*)att_s)[jc];
    const float4 da4 = ((const float4*)att_d)[jc];
#pragma unroll
    for (int r = 0; r < 4; r++) {
        const int node = n0 + ng * 4 + r;
        const bool ok  = node < NN;
        if (ok) ((float4*)h)[node * 16 + jc] = acc[r];
        float ps = acc[r].x * sa4.x + acc[r].y * sa4.y + acc[r].z * sa4.z + acc[r].w * sa4.w;
        float pd = acc[r].x * da4.x + acc[r].y * da4.y + acc[r].z * da4.z + acc[r].w * da4.w;
        ps += __shfl_down(ps, 8);  pd += __shfl_down(pd, 8);
        ps += __shfl_down(ps, 4);  pd += __shfl_down(pd, 4);
        ps += __shfl_down(ps, 2);  pd += __shfl_down(pd, 2);
        ps += __shfl_down(ps, 1);  pd += __shfl_down(pd, 1);
        if (ok && jc == 0) { as[node] = ps; ad[node] = pd; }
    }
}

// ---------------------------------------------------------------------------
// CSR build: count -> scan (3 kernels) -> scatter. (unchanged, verified R2)
// ---------------------------------------------------------------------------
__global__ void count_kernel(const int* __restrict__ ei, int* __restrict__ cnt)
{
    const int e = blockIdx.x * 256 + threadIdx.x;
    if (e >= NET) return;
    const int d = (e < NE) ? ei[NE + e] : e - NE;
    atomicAdd(&cnt[d], 1);
}

__global__ __launch_bounds__(256) void scanA_kernel(const int* __restrict__ cnt,
                                                    int* __restrict__ excl,
                                                    int* __restrict__ bsum)
{
    __shared__ int sh[256];
    const int tid = threadIdx.x;
    const int i   = blockIdx.x * 256 + tid;
    const int v   = (i < NN) ? cnt[i] : 0;
    sh[tid] = v;
    __syncthreads();
#pragma unroll
    for (int off = 1; off < 256; off <<= 1) {
        int t = (tid >= off) ? sh[tid - off] : 0;
        __syncthreads();
        sh[tid] += t;
        __syncthreads();
    }
    if (i < NN) excl[i] = sh[tid] - v;
    if (tid == 255) bsum[blockIdx.x] = sh[255];
}

__global__ __launch_bounds__(256) void scanB_kernel(int* __restrict__ bsum,
                                                    int* __restrict__ boff)
{
    __shared__ int sh[256];
    const int tid = threadIdx.x;
    const int v   = (tid < NB) ? bsum[tid] : 0;
    sh[tid] = v;
    __syncthreads();
#pragma unroll
    for (int off = 1; off < 256; off <<= 1) {
        int t = (tid >= off) ? sh[tid - off] : 0;
        __syncthreads();
        sh[tid] += t;
        __syncthreads();
    }
    if (tid < NB) boff[tid] = sh[tid] - v;
}

__global__ void scanC_kernel(const int* __restrict__ excl, const int* __restrict__ boff,
                             int* __restrict__ row_ptr, int* __restrict__ cursor)
{
    const int i = blockIdx.x * 256 + threadIdx.x;
    if (i < NN) {
        int r = excl[i] + boff[i >> 8];
        row_ptr[i] = r;
        cursor[i]  = r;
    } else if (i == NN) {
        row_ptr[NN] = NET;
    }
}

__global__ void scatter_kernel(const int* __restrict__ ei, int* __restrict__ cursor,
                               int* __restrict__ col)
{
    const int e = blockIdx.x * 256 + threadIdx.x;
    if (e >= NET) return;
    int s, d;
    if (e < NE) { s = ei[e]; d = ei[NE + e]; } else { s = d = e - NE; }
    const int slot = atomicAdd(&cursor[d], 1);
    col[slot] = s;
}

// ---------------------------------------------------------------------------
// Fused layer-1 tail: one wave per dst; fp16-packed gather (1 dword/edge);
// lane owns ch {2l,2l+1}, single head per lane (head = lane>>4);
// src indices via readlane (SGPR) -> as-fetch becomes scalar load.
// ---------------------------------------------------------------------------
__global__ __launch_bounds__(256) void agg1_fused_kernel(
    const int* __restrict__ row_ptr, const int* __restrict__ col,
    const unsigned* __restrict__ hh, const float* __restrict__ as,
    const float* __restrict__ ad, const float* __restrict__ b1,
    float* __restrict__ act)
{
    const int d    = (blockIdx.x * 256 + threadIdx.x) >> 6;
    const int lane = threadIdx.x & 63;
    if (d >= NN) return;
    const int head = lane >> 4;
    const float4 adv = ((const float4*)ad)[d];
    const float ad_s = (head & 2) ? ((head & 1) ? adv.w : adv.z)
                                  : ((head & 1) ? adv.y : adv.x);
    const int beg = row_ptr[d], end = row_ptr[d + 1];   // deg >= 1 (self loop)

    float acc0 = 0.f, acc1 = 0.f, den = 0.f;

    for (int jb = beg; jb < end; jb += 64) {
        const int cnt = min(64, end - jb);
        const int sv  = col[jb + min(lane, cnt - 1)];
        for (int u = 0; u < cnt; u += 8) {
            int s[8];
#pragma unroll
            for (int k = 0; k < 8; k++)
                s[k] = __builtin_amdgcn_readlane(sv, min(u + k, cnt - 1));
            float4   av[8];
            unsigned g[8];
#pragma unroll
            for (int k = 0; k < 8; k++) {
                av[k] = ((const float4*)as)[s[k]];
                g[k]  = hh[s[k] * 64 + lane];
            }
#pragma unroll
            for (int k = 0; k < 8; k++) {
                const float m = (u + k < cnt) ? 1.f : 0.f;
                const float a = (head & 2) ? ((head & 1) ? av[k].w : av[k].z)
                                           : ((head & 1) ? av[k].y : av[k].x);
                const float w = __expf(lrelu(a + ad_s)) * m;
                const float2 g2 = unpk16(g[k]);
                den  += w;
                acc0 += w * g2.x;
                acc1 += w * g2.y;
            }
        }
    }
    const float2 bb  = ((const float2*)b1)[lane];
    const float  inv = 1.f / (den + 1e-16f);
    float v0 = acc0 * inv + bb.x;
    float v1 = acc1 * inv + bb.y;
    v0 = v0 > 0.f ? v0 : (__expf(v0) - 1.f);
    v1 = v1 > 0.f ? v1 : (__expf(v1) - 1.f);
    ((float2*)act)[d * 64 + lane] = make_float2(v0, v1);
}

// ---------------------------------------------------------------------------
// Fused layer-2 tail: 2 edges per wave pass (32 lanes/edge, float2 gathers),
// cross-half shfl_xor reduce in epilogue. fp32 gathers (accuracy headroom).
// ---------------------------------------------------------------------------
__global__ __launch_bounds__(256) void agg2_fused_kernel(
    const int* __restrict__ row_ptr, const int* __restrict__ col,
    const float* __restrict__ h, const float* __restrict__ as,
    const float* __restrict__ ad, const float* __restrict__ b2,
    float* __restrict__ out)
{
    const int d    = (blockIdx.x * 256 + threadIdx.x) >> 6;
    const int lane = threadIdx.x & 63;
    if (d >= NN) return;
    const int  hf  = lane >> 5;
    const int  p   = lane & 31;
    const float adv = ad[d];
    const int beg = row_ptr[d], end = row_ptr[d + 1];

    float acc0 = 0.f, acc1 = 0.f, den = 0.f;
    for (int jb = beg; jb < end; jb += 64) {
        const int cnt = min(64, end - jb);
        const int sv  = col[jb + min(lane, cnt - 1)];
        for (int u = 0; u < cnt; u += 8) {        // 4 edge-pairs per unroll
            int sa[4], sb[4], s[4];
#pragma unroll
            for (int q = 0; q < 4; q++) {
                sa[q] = __builtin_amdgcn_readlane(sv, min(u + 2 * q,     cnt - 1));
                sb[q] = __builtin_amdgcn_readlane(sv, min(u + 2 * q + 1, cnt - 1));
            }
#pragma unroll
            for (int q = 0; q < 4; q++) s[q] = hf ? sb[q] : sa[q];
            float  a[4];
            float2 g[4];
#pragma unroll
            for (int q = 0; q < 4; q++) {
                a[q] = as[s[q]];
                g[q] = ((const float2*)h)[s[q] * 32 + p];
            }
#pragma unroll
            for (int q = 0; q < 4; q++) {
                const float m = (u + 2 * q + hf < cnt) ? 1.f : 0.f;
                const float w = __expf(lrelu(a[q] + adv)) * m;
                den  += w;
                acc0 += w * g[q].x;
                acc1 += w * g[q].y;
            }
        }
    }
    den  += __shfl_xor(den, 32);
    acc0 += __shfl_xor(acc0, 32);
    acc1 += __shfl_xor(acc1, 32);
    if (hf == 0) {
        const float2 bb  = ((const float2*)b2)[p];
        const float  inv = 1.f / (den + 1e-16f);
        ((float2*)out)[d * 32 + p] = make_float2(acc0 * inv + bb.x, acc1 * inv + bb.y);
    }
}

// ---------------------------------------------------------------------------
extern "C" void kernel_launch(void* const* d_in, const int* in_sizes, int n_in,
                              void* d_out, int out_size, void* d_ws, size_t ws_size,
                              hipStream_t stream)
{
    const float* x    = (const float*)d_in[0];
    const int*   ei   = (const int*)  d_in[1];
    const float* W1   = (const float*)d_in[2];
    const float* at_s1= (const float*)d_in[3];
    const float* at_d1= (const float*)d_in[4];
    const float* b1   = (const float*)d_in[5];
    const float* W2   = (const float*)d_in[6];
    const float* at_s2= (const float*)d_in[7];
    const float* at_d2= (const float*)d_in[8];
    const float* b2   = (const float*)d_in[9];
    float*       out  = (float*)d_out;

    // workspace layout
    float* fw   = (float*)d_ws;
    float* act1 = fw;                  // NN*128  fp32 (gemm2 input)
    float* h2   = act1 + NN * 128;     // NN*64   fp32
    float* as1  = h2   + NN * 64;      // NN*4
    float* ad1  = as1  + NN * 4;       // NN*4
    float* as2  = ad1  + NN * 4;       // NN
    float* ad2  = as2  + NN;           // NN
    unsigned* hh = (unsigned*)(ad2 + NN);  // NN*64 (fp16-packed h1)
    int*   cnt     = (int*)(hh + NN * 64); // NN   (zeroed)
    int*   excl    = cnt     + NN;     // NN
    int*   row_ptr = excl    + NN;     // NN+1
    int*   cursor  = row_ptr + NN + 1; // NN
    int*   bsum    = cursor  + NN;     // 256
    int*   boff    = bsum    + 256;    // 256
    int*   col     = boff    + 256;    // NET

    hipMemsetAsync(cnt, 0, NN * sizeof(int), stream);

    const int eg = (NET + 255) / 256;
    count_kernel  <<<eg, 256, 0, stream>>>(ei, cnt);
    scanA_kernel  <<<NB, 256, 0, stream>>>(cnt, excl, bsum);
    scanB_kernel  <<<1,  256, 0, stream>>>(bsum, boff);
    scanC_kernel  <<<(NN + 256) / 256 + 1, 256, 0, stream>>>(excl, boff, row_ptr, cursor);
    scatter_kernel<<<eg, 256, 0, stream>>>(ei, cursor, col);

    const int gemm_grid = (NN + 63) / 64;
    const int node_wave_grid = (NN + 3) / 4;

    // layer 1
    gemm1_alpha_kernel<<<gemm_grid, 256, 0, stream>>>(x, W1, at_s1, at_d1, hh, as1, ad1);
    agg1_fused_kernel <<<node_wave_grid, 256, 0, stream>>>(row_ptr, col, hh, as1, ad1, b1, act1);

    // layer 2
    gemm2_alpha_kernel<<<gemm_grid, 256, 0, stream>>>(act1, W2, at_s2, at_d2, h2, as2, ad2);
    agg2_fused_kernel <<<node_wave_grid, 256, 0, stream>>>(row_ptr, col, h2, as2, ad2, b2, out);
}

// Round 5
// 304.793 us; speedup vs baseline: 3.1559x; 1.1184x over previous
//
#include <hip/hip_runtime.h>

#define NN    50000      // nodes
#define NE    800000     // edges (without self loops)
#define NET   850000     // NE + NN (with self loops)
#define NBUCK ((NN + 255) / 256)   // 196 dst-buckets of 256 nodes
#define MAXB  8192       // LDS capacity per bucket (avg 4352, sigma 66)

typedef __fp16 half2_t __attribute__((ext_vector_type(2)));

__device__ __forceinline__ float lrelu(float v) { return fmaxf(v, 0.2f * v); }
__device__ __forceinline__ float4 f4zero() { return make_float4(0.f, 0.f, 0.f, 0.f); }
__device__ __forceinline__ unsigned pk16(float a, float b) {
    half2_t h = __builtin_amdgcn_cvt_pkrtz(a, b);
    return __builtin_bit_cast(unsigned, h);
}
__device__ __forceinline__ float2 unpk16(unsigned u) {
    half2_t h = __builtin_bit_cast(half2_t, u);
    return make_float2((float)h.x, (float)h.y);
}

// ---------------------------------------------------------------------------
// GEMM1 + alpha1 fused (unchanged, verified R4)
// ---------------------------------------------------------------------------
__global__ __launch_bounds__(256) void gemm1_alpha_kernel(
    const float* __restrict__ x, const float* __restrict__ W,
    const float* __restrict__ att_s, const float* __restrict__ att_d,
    unsigned* __restrict__ hh, float* __restrict__ as, float* __restrict__ ad)
{
    __shared__ float Ws[64 * 128];
    __shared__ float xs[64 * 64];
    const int t  = threadIdx.x;
    const int n0 = blockIdx.x * 64;
    const int jc = t & 31;
    const int ng = t >> 5;

    float4 acc[8];
#pragma unroll
    for (int r = 0; r < 8; r++) acc[r] = f4zero();

    float4*       Ws4 = (float4*)Ws;
    float4*       xs4 = (float4*)xs;
    const float4* x4  = (const float4*)x;

    for (int kc = 0; kc < 128; kc += 64) {
        const float4* W4 = (const float4*)(W + kc * 128);
        for (int i = t; i < 64 * 32; i += 256) Ws4[i] = W4[i];
        for (int i = t; i < 64 * 16; i += 256) {
            int node = n0 + (i >> 4);
            xs4[i] = (node < NN) ? x4[node * 32 + (kc >> 2) + (i & 15)] : f4zero();
        }
        __syncthreads();

        for (int kk = 0; kk < 64; kk += 4) {
            float4 w0 = Ws4[(kk + 0) * 32 + jc];
            float4 w1 = Ws4[(kk + 1) * 32 + jc];
            float4 w2 = Ws4[(kk + 2) * 32 + jc];
            float4 w3 = Ws4[(kk + 3) * 32 + jc];
#pragma unroll
            for (int r = 0; r < 8; r++) {
                float4 xv = xs4[((ng * 8 + r) * 64 + kk) >> 2];
                acc[r].x += xv.x * w0.x + xv.y * w1.x + xv.z * w2.x + xv.w * w3.x;
                acc[r].y += xv.x * w0.y + xv.y * w1.y + xv.z * w2.y + xv.w * w3.y;
                acc[r].z += xv.x * w0.z + xv.y * w1.z + xv.z * w2.z + xv.w * w3.z;
                acc[r].w += xv.x * w0.w + xv.y * w1.w + xv.z * w2.w + xv.w * w3.w;
            }
        }
        __syncthreads();
    }

    const float4 sa4 = ((const float4*)att_s)[jc];
    const float4 da4 = ((const float4*)att_d)[jc];
#pragma unroll
    for (int r = 0; r < 8; r++) {
        const int node = n0 + ng * 8 + r;
        const bool ok  = node < NN;
        if (ok) {
            uint2 hp;
            hp.x = pk16(acc[r].x, acc[r].y);
            hp.y = pk16(acc[r].z, acc[r].w);
            ((uint2*)hh)[node * 32 + jc] = hp;
        }
        float ps = acc[r].x * sa4.x + acc[r].y * sa4.y + acc[r].z * sa4.z + acc[r].w * sa4.w;
        float pd = acc[r].x * da4.x + acc[r].y * da4.y + acc[r].z * da4.z + acc[r].w * da4.w;
        ps += __shfl_down(ps, 4);  pd += __shfl_down(pd, 4);
        ps += __shfl_down(ps, 2);  pd += __shfl_down(pd, 2);
        ps += __shfl_down(ps, 1);  pd += __shfl_down(pd, 1);
        if (ok && (jc & 7) == 0) {
            as[node * 4 + (jc >> 3)] = ps;
            ad[node * 4 + (jc >> 3)] = pd;
        }
    }
}

// ---------------------------------------------------------------------------
// GEMM2 + alpha2 fused (unchanged, verified R4)
// ---------------------------------------------------------------------------
__global__ __launch_bounds__(256) void gemm2_alpha_kernel(
    const float* __restrict__ x, const float* __restrict__ W,
    const float* __restrict__ att_s, const float* __restrict__ att_d,
    float* __restrict__ h, float* __restrict__ as, float* __restrict__ ad)
{
    __shared__ float Ws[128 * 64];
    __shared__ float xs[64 * 64];
    const int t  = threadIdx.x;
    const int n0 = blockIdx.x * 64;
    const int jc = t & 15;
    const int ng = t >> 4;

    float4 acc[4];
#pragma unroll
    for (int r = 0; r < 4; r++) acc[r] = f4zero();

    float4*       Ws4 = (float4*)Ws;
    float4*       xs4 = (float4*)xs;
    const float4* x4  = (const float4*)x;

    for (int i = t; i < 128 * 16; i += 256) Ws4[i] = ((const float4*)W)[i];

    for (int kc = 0; kc < 128; kc += 64) {
        __syncthreads();
        for (int i = t; i < 64 * 16; i += 256) {
            int node = n0 + (i >> 4);
            xs4[i] = (node < NN) ? x4[node * 32 + (kc >> 2) + (i & 15)] : f4zero();
        }
        __syncthreads();

        for (int kk = 0; kk < 64; kk += 4) {
            float4 w0 = Ws4[(kc + kk + 0) * 16 + jc];
            float4 w1 = Ws4[(kc + kk + 1) * 16 + jc];
            float4 w2 = Ws4[(kc + kk + 2) * 16 + jc];
            float4 w3 = Ws4[(kc + kk + 3) * 16 + jc];
#pragma unroll
            for (int r = 0; r < 4; r++) {
                float4 xv = xs4[((ng * 4 + r) * 64 + kk) >> 2];
                acc[r].x += xv.x * w0.x + xv.y * w1.x + xv.z * w2.x + xv.w * w3.x;
                acc[r].y += xv.x * w0.y + xv.y * w1.y + xv.z * w2.y + xv.w * w3.y;
                acc[r].z += xv.x * w0.z + xv.y * w1.z + xv.z * w2.z + xv.w * w3.z;
                acc[r].w += xv.x * w0.w + xv.y * w1.w + xv.z * w2.w + xv.w * w3.w;
            }
        }
    }

    const float4 sa4 = ((const float4*)att_s)[jc];
    const float4 da4 = ((const float4*)att_d)[jc];
#pragma unroll
    for (int r = 0; r < 4; r++) {
        const int node = n0 + ng * 4 + r;
        const bool ok  = node < NN;
        if (ok) ((float4*)h)[node * 16 + jc] = acc[r];
        float ps = acc[r].x * sa4.x + acc[r].y * sa4.y + acc[r].z * sa4.z + acc[r].w * sa4.w;
        float pd = acc[r].x * da4.x + acc[r].y * da4.y + acc[r].z * da4.z + acc[r].w * da4.w;
        ps += __shfl_down(ps, 8);  pd += __shfl_down(pd, 8);
        ps += __shfl_down(ps, 4);  pd += __shfl_down(pd, 4);
        ps += __shfl_down(ps, 2);  pd += __shfl_down(pd, 2);
        ps += __shfl_down(ps, 1);  pd += __shfl_down(pd, 1);
        if (ok && jc == 0) { as[node] = ps; ad[node] = pd; }
    }
}

// ---------------------------------------------------------------------------
// CSR build v2: bucket histogram -> bucket scan -> bin pairs -> per-bucket
// LDS counting sort (also emits row_ptr). No per-edge global atomics on hot
// counters; col written fully coalesced.
// ---------------------------------------------------------------------------
__global__ __launch_bounds__(1024) void bcount_kernel(const int* __restrict__ ei,
                                                      int* __restrict__ bcnt)
{
    __shared__ int lh[NBUCK];
    const int t = threadIdx.x;
    if (t < NBUCK) lh[t] = 0;
    __syncthreads();
    const int e = blockIdx.x * 1024 + t;
    if (e < NET) {
        const int d = (e < NE) ? ei[NE + e] : e - NE;
        atomicAdd(&lh[d >> 8], 1);
    }
    __syncthreads();
    if (t < NBUCK && lh[t]) atomicAdd(&bcnt[t], lh[t]);
}

__global__ __launch_bounds__(256) void bscan_kernel(const int* __restrict__ bcnt,
                                                    int* __restrict__ boff,
                                                    int* __restrict__ bcursor,
                                                    int* __restrict__ row_ptr)
{
    __shared__ int sh[256];
    const int t = threadIdx.x;
    const int v = (t < NBUCK) ? bcnt[t] : 0;
    sh[t] = v;
    __syncthreads();
#pragma unroll
    for (int off = 1; off < 256; off <<= 1) {
        int u = (t >= off) ? sh[t - off] : 0;
        __syncthreads();
        sh[t] += u;
        __syncthreads();
    }
    if (t < NBUCK) {
        const int ex = sh[t] - v;
        boff[t]    = ex;
        bcursor[t] = ex;
    }
    if (t == 0) { boff[NBUCK] = NET; row_ptr[NN] = NET; }
}

__global__ __launch_bounds__(1024) void bin_kernel(const int* __restrict__ ei,
                                                   int* __restrict__ bcursor,
                                                   uint2* __restrict__ pairs)
{
    __shared__ int hist[NBUCK], base[NBUCK], cur[NBUCK];
    const int t = threadIdx.x;
    if (t < NBUCK) { hist[t] = 0; cur[t] = 0; }
    __syncthreads();
    const int e = blockIdx.x * 1024 + t;
    int s = 0, d = 0, bk = 0;
    const bool ok = e < NET;
    if (ok) {
        if (e < NE) { s = ei[e]; d = ei[NE + e]; } else { s = d = e - NE; }
        bk = d >> 8;
        atomicAdd(&hist[bk], 1);
    }
    __syncthreads();
    if (t < NBUCK && hist[t]) base[t] = atomicAdd(&bcursor[t], hist[t]);
    __syncthreads();
    if (ok) {
        const int r = atomicAdd(&cur[bk], 1);
        pairs[base[bk] + r] = make_uint2((unsigned)s, (unsigned)d);
    }
}

__global__ __launch_bounds__(512) void bsort_kernel(const int* __restrict__ boff,
                                                    const uint2* __restrict__ pairs,
                                                    int* __restrict__ row_ptr,
                                                    int* __restrict__ col)
{
    __shared__ int hist[256], cur[256], sh[256];
    __shared__ int outl[MAXB];
    const int b = blockIdx.x, t = threadIdx.x;
    const int gbeg = boff[b], gend = boff[b + 1];
    const int m = gend - gbeg;
    if (t < 256) hist[t] = 0;
    __syncthreads();
    for (int i = t; i < m; i += 512)
        atomicAdd(&hist[pairs[gbeg + i].y & 255], 1);
    __syncthreads();
    if (t < 256) sh[t] = hist[t];
    __syncthreads();
#pragma unroll
    for (int off = 1; off < 256; off <<= 1) {
        int u = (t < 256 && t >= off) ? sh[t - off] : 0;
        __syncthreads();
        if (t < 256) sh[t] += u;
        __syncthreads();
    }
    if (t < 256) {
        const int ex = sh[t] - hist[t];
        cur[t] = ex;
        const int node = (b << 8) + t;
        if (node < NN) row_ptr[node] = gbeg + ex;
    }
    __syncthreads();
    for (int i = t; i < m; i += 512) {
        const uint2 p = pairs[gbeg + i];
        const int r = atomicAdd(&cur[p.y & 255], 1);
        outl[r] = (int)p.x;
    }
    __syncthreads();
    for (int i = t; i < m; i += 512) col[gbeg + i] = outl[i];
}

// ---------------------------------------------------------------------------
// Fused layer-1 tail (unchanged, verified R4)
// ---------------------------------------------------------------------------
__global__ __launch_bounds__(256) void agg1_fused_kernel(
    const int* __restrict__ row_ptr, const int* __restrict__ col,
    const unsigned* __restrict__ hh, const float* __restrict__ as,
    const float* __restrict__ ad, const float* __restrict__ b1,
    float* __restrict__ act)
{
    const int d    = (blockIdx.x * 256 + threadIdx.x) >> 6;
    const int lane = threadIdx.x & 63;
    if (d >= NN) return;
    const int head = lane >> 4;
    const float4 adv = ((const float4*)ad)[d];
    const float ad_s = (head & 2) ? ((head & 1) ? adv.w : adv.z)
                                  : ((head & 1) ? adv.y : adv.x);
    const int beg = row_ptr[d], end = row_ptr[d + 1];

    float acc0 = 0.f, acc1 = 0.f, den = 0.f;

    for (int jb = beg; jb < end; jb += 64) {
        const int cnt = min(64, end - jb);
        const int sv  = col[jb + min(lane, cnt - 1)];
        for (int u = 0; u < cnt; u += 8) {
            int s[8];
#pragma unroll
            for (int k = 0; k < 8; k++)
                s[k] = __builtin_amdgcn_readlane(sv, min(u + k, cnt - 1));
            float4   av[8];
            unsigned g[8];
#pragma unroll
            for (int k = 0; k < 8; k++) {
                av[k] = ((const float4*)as)[s[k]];
                g[k]  = hh[s[k] * 64 + lane];
            }
#pragma unroll
            for (int k = 0; k < 8; k++) {
                const float m = (u + k < cnt) ? 1.f : 0.f;
                const float a = (head & 2) ? ((head & 1) ? av[k].w : av[k].z)
                                           : ((head & 1) ? av[k].y : av[k].x);
                const float w = __expf(lrelu(a + ad_s)) * m;
                const float2 g2 = unpk16(g[k]);
                den  += w;
                acc0 += w * g2.x;
                acc1 += w * g2.y;
            }
        }
    }
    const float2 bb  = ((const float2*)b1)[lane];
    const float  inv = 1.f / (den + 1e-16f);
    float v0 = acc0 * inv + bb.x;
    float v1 = acc1 * inv + bb.y;
    v0 = v0 > 0.f ? v0 : (__expf(v0) - 1.f);
    v1 = v1 > 0.f ? v1 : (__expf(v1) - 1.f);
    ((float2*)act)[d * 64 + lane] = make_float2(v0, v1);
}

// ---------------------------------------------------------------------------
// Fused layer-2 tail (unchanged, verified R4)
// ---------------------------------------------------------------------------
__global__ __launch_bounds__(256) void agg2_fused_kernel(
    const int* __restrict__ row_ptr, const int* __restrict__ col,
    const float* __restrict__ h, const float* __restrict__ as,
    const float* __restrict__ ad, const float* __restrict__ b2,
    float* __restrict__ out)
{
    const int d    = (blockIdx.x * 256 + threadIdx.x) >> 6;
    const int lane = threadIdx.x & 63;
    if (d >= NN) return;
    const int  hf  = lane >> 5;
    const int  p   = lane & 31;
    const float adv = ad[d];
    const int beg = row_ptr[d], end = row_ptr[d + 1];

    float acc0 = 0.f, acc1 = 0.f, den = 0.f;
    for (int jb = beg; jb < end; jb += 64) {
        const int cnt = min(64, end - jb);
        const int sv  = col[jb + min(lane, cnt - 1)];
        for (int u = 0; u < cnt; u += 8) {
            int sa[4], sb[4], s[4];
#pragma unroll
            for (int q = 0; q < 4; q++) {
                sa[q] = __builtin_amdgcn_readlane(sv, min(u + 2 * q,     cnt - 1));
                sb[q] = __builtin_amdgcn_readlane(sv, min(u + 2 * q + 1, cnt - 1));
            }
#pragma unroll
            for (int q = 0; q < 4; q++) s[q] = hf ? sb[q] : sa[q];
            float  a[4];
            float2 g[4];
#pragma unroll
            for (int q = 0; q < 4; q++) {
                a[q] = as[s[q]];
                g[q] = ((const float2*)h)[s[q] * 32 + p];
            }
#pragma unroll
            for (int q = 0; q < 4; q++) {
                const float m = (u + 2 * q + hf < cnt) ? 1.f : 0.f;
                const float w = __expf(lrelu(a[q] + adv)) * m;
                den  += w;
                acc0 += w * g[q].x;
                acc1 += w * g[q].y;
            }
        }
    }
    den  += __shfl_xor(den, 32);
    acc0 += __shfl_xor(acc0, 32);
    acc1 += __shfl_xor(acc1, 32);
    if (hf == 0) {
        const float2 bb  = ((const float2*)b2)[p];
        const float  inv = 1.f / (den + 1e-16f);
        ((float2*)out)[d * 32 + p] = make_float2(acc0 * inv + bb.x, acc1 * inv + bb.y);
    }
}

// ---------------------------------------------------------------------------
extern "C" void kernel_launch(void* const* d_in, const int* in_sizes, int n_in,
                              void* d_out, int out_size, void* d_ws, size_t ws_size,
                              hipStream_t stream)
{
    const float* x    = (const float*)d_in[0];
    const int*   ei   = (const int*)  d_in[1];
    const float* W1   = (const float*)d_in[2];
    const float* at_s1= (const float*)d_in[3];
    const float* at_d1= (const float*)d_in[4];
    const float* b1   = (const float*)d_in[5];
    const float* W2   = (const float*)d_in[6];
    const float* at_s2= (const float*)d_in[7];
    const float* at_d2= (const float*)d_in[8];
    const float* b2   = (const float*)d_in[9];
    float*       out  = (float*)d_out;

    // workspace layout
    float* fw   = (float*)d_ws;
    float* act1 = fw;                  // NN*128  fp32 (gemm2 input)
    float* h2   = act1 + NN * 128;     // NN*64   fp32
    float* as1  = h2   + NN * 64;      // NN*4
    float* ad1  = as1  + NN * 4;       // NN*4
    float* as2  = ad1  + NN * 4;       // NN
    float* ad2  = as2  + NN;           // NN
    unsigned* hh = (unsigned*)(ad2 + NN);  // NN*64 (fp16-packed h1)
    uint2* pairs = (uint2*)hh;             // NET*2 ints — consumed before hh written
    int*   row_ptr = (int*)(hh + NN * 64); // NN+1
    int*   col     = row_ptr + NN + 1;     // NET
    int*   bcnt    = col  + NET;           // 256 (zeroed)
    int*   boff    = bcnt + 256;           // 256
    int*   bcursor = boff + 256;           // 256

    hipMemsetAsync(bcnt, 0, 256 * sizeof(int), stream);

    const int eg1024 = (NET + 1023) / 1024;
    bcount_kernel<<<eg1024, 1024, 0, stream>>>(ei, bcnt);
    bscan_kernel <<<1, 256, 0, stream>>>(bcnt, boff, bcursor, row_ptr);
    bin_kernel   <<<eg1024, 1024, 0, stream>>>(ei, bcursor, pairs);
    bsort_kernel <<<NBUCK, 512, 0, stream>>>(boff, pairs, row_ptr, col);

    const int gemm_grid = (NN + 63) / 64;
    const int node_wave_grid = (NN + 3) / 4;

    // layer 1
    gemm1_alpha_kernel<<<gemm_grid, 256, 0, stream>>>(x, W1, at_s1, at_d1, hh, as1, ad1);
    agg1_fused_kernel <<<node_wave_grid, 256, 0, stream>>>(row_ptr, col, hh, as1, ad1, b1, act1);

    // layer 2
    gemm2_alpha_kernel<<<gemm_grid, 256, 0, stream>>>(act1, W2, at_s2, at_d2, h2, as2, ad2);
    agg2_fused_kernel <<<node_wave_grid, 256, 0, stream>>>(row_ptr, col, h2, as2, ad2, b2, out);
}